// Round 4
// baseline (663.068 us; speedup 1.0000x reference)
//
#include <hip/hip_runtime.h>
#include <cstdint>

typedef unsigned short u16;
typedef __attribute__((ext_vector_type(8))) __bf16 bf16x8;
typedef __attribute__((ext_vector_type(4))) float f32x4;

#define S_LEN 2048

__device__ __forceinline__ u16 f2bf(float f) {
  uint32_t u = __builtin_bit_cast(uint32_t, f);
  u += 0x7fffu + ((u >> 16) & 1u);
  return (u16)(u >> 16);
}
__device__ __forceinline__ float bf2f(u16 h) {
  return __builtin_bit_cast(float, (uint32_t)h << 16);
}
__device__ __forceinline__ bf16x8 ldfrag(const u16* p) {
  return __builtin_bit_cast(bf16x8, *(const uint4*)p);
}
__device__ __forceinline__ f32x4 mfma16(bf16x8 a, bf16x8 b, f32x4 c) {
  return __builtin_amdgcn_mfma_f32_16x16x32_bf16(a, b, c, 0, 0, 0);
}

// ---------------- fp32 -> bf16 convert (vectorized) ----------------
__global__ __launch_bounds__(256) void cvt_kernel(const float* __restrict__ in,
                                                  u16* __restrict__ out, int n4) {
  int i = blockIdx.x * 256 + threadIdx.x;
  if (i >= n4) return;
  float4 v = ((const float4*)in)[i];
  ushort4 o;
  o.x = f2bf(v.x); o.y = f2bf(v.y); o.z = f2bf(v.z); o.w = f2bf(v.w);
  ((ushort4*)out)[i] = o;
}

// ------------- fp32 W[K][N] -> bf16 Wt[N][K] (transpose-convert) -------------
__global__ __launch_bounds__(256) void cvtT_kernel(const float* __restrict__ W,
                                                   u16* __restrict__ Wt, int K, int N) {
  __shared__ float t[32][33];
  int tx = threadIdx.x & 31, ty = threadIdx.x >> 5;  // ty 0..7
  int n0 = blockIdx.x * 32, k0 = blockIdx.y * 32;
#pragma unroll
  for (int j = 0; j < 4; ++j)
    t[ty + 8 * j][tx] = W[(long)(k0 + ty + 8 * j) * N + n0 + tx];
  __syncthreads();
#pragma unroll
  for (int j = 0; j < 4; ++j)
    Wt[(long)(n0 + ty + 8 * j) * K + k0 + tx] = f2bf(t[tx][ty + 8 * j]);
}

// ------------- GEMM: C[M][ldc] = A[M][K](bf16) * Bt[N][K]^T(bf16) -------------
// 128x128 tile, 4 waves (2x2), BK=32, LDS k-stride padded to 40 elems.
// MODE: 0 = fp32 out, 1 = bf16 out, 2 = bf16 out transposed per-head (Vt[b][kvh][d][s])
#define LDT 40
template <int MODE>
__global__ __launch_bounds__(256) void gemm_bt(const u16* __restrict__ A,
                                               const u16* __restrict__ Bt,
                                               void* __restrict__ C, int K, int ldc) {
  __shared__ u16 As[128 * LDT];
  __shared__ u16 Bs[128 * LDT];
  int tid = threadIdx.x;
  int lane = tid & 63, w = tid >> 6;
  int wr = (w >> 1) * 64, wc = (w & 1) * 64;
  int l15 = lane & 15, l4 = lane >> 4;
  int rowbase = blockIdx.x * 128, colbase = blockIdx.y * 128;
  f32x4 acc[4][4] = {};
  int r0 = tid >> 2, kc0 = (tid & 3) * 8;
  const u16* Ap = A + (long)(rowbase + r0) * K + kc0;
  const u16* Bp = Bt + (long)(colbase + r0) * K + kc0;
  u16* Asw = &As[r0 * LDT + kc0];
  u16* Bsw = &Bs[r0 * LDT + kc0];
  for (int k0 = 0; k0 < K; k0 += 32) {
    __syncthreads();
    uint4 a0 = *(const uint4*)(Ap + k0);
    uint4 a1 = *(const uint4*)(Ap + (long)64 * K + k0);
    uint4 b0 = *(const uint4*)(Bp + k0);
    uint4 b1 = *(const uint4*)(Bp + (long)64 * K + k0);
    *(uint4*)Asw = a0;
    *(uint4*)(Asw + 64 * LDT) = a1;
    *(uint4*)Bsw = b0;
    *(uint4*)(Bsw + 64 * LDT) = b1;
    __syncthreads();
    bf16x8 af[4], bv[4];
#pragma unroll
    for (int m = 0; m < 4; ++m) af[m] = ldfrag(&As[(wr + m * 16 + l15) * LDT + l4 * 8]);
#pragma unroll
    for (int n = 0; n < 4; ++n) bv[n] = ldfrag(&Bs[(wc + n * 16 + l15) * LDT + l4 * 8]);
#pragma unroll
    for (int m = 0; m < 4; ++m)
#pragma unroll
      for (int n = 0; n < 4; ++n) acc[m][n] = mfma16(af[m], bv[n], acc[m][n]);
  }
#pragma unroll
  for (int m = 0; m < 4; ++m)
#pragma unroll
    for (int n = 0; n < 4; ++n) {
      if (MODE == 2) {
        // Vt[b][kvh][d][s] transposed write: 4 consecutive s per lane -> 8B store
        int row = rowbase + wr + m * 16 + l4 * 4;  // = b*2048 + s, s%4==0
        int col = colbase + wc + n * 16 + l15;     // = kvh*64 + d
        int b_ = row >> 11, s_ = row & 2047;
        int kvh_ = col >> 6, d_ = col & 63;
        ushort4 pk;
        pk.x = f2bf(acc[m][n][0]); pk.y = f2bf(acc[m][n][1]);
        pk.z = f2bf(acc[m][n][2]); pk.w = f2bf(acc[m][n][3]);
        *(ushort4*)&((u16*)C)[((long)((b_ * 8 + kvh_) * 64 + d_)) * 2048 + s_] = pk;
      } else {
#pragma unroll
        for (int r = 0; r < 4; ++r) {
          int row = rowbase + wr + m * 16 + l4 * 4 + r;
          int col = colbase + wc + n * 16 + l15;
          if (MODE == 1)
            ((u16*)C)[(long)row * ldc + col] = f2bf(acc[m][n][r]);
          else
            ((float*)C)[(long)row * ldc + col] = acc[m][n][r];
        }
      }
    }
}

// ---------------- RoPE (interleaved pairs), optional score-scale fold ----------------
__global__ __launch_bounds__(256) void rope_kernel(u16* __restrict__ T, int log2H,
                                                   float scale, int total) {
  int p = blockIdx.x * 256 + threadIdx.x;
  if (p >= total) return;
  int i = p & 31;
  int s = (p >> (5 + log2H)) & (S_LEN - 1);
  float freq = exp2f(-(float)i * (13.287712379549449f / 32.0f));  // theta^(-i/32)
  float ang = (float)s * freq;
  float sn, cs;
  sincosf(ang, &sn, &cs);
  uint32_t v = ((uint32_t*)T)[p];
  float e = bf2f((u16)(v & 0xffff)), o = bf2f((u16)(v >> 16));
  float re = (e * cs - o * sn) * scale;
  float ro = (e * sn + o * cs) * scale;
  ((uint32_t*)T)[p] = (uint32_t)f2bf(re) | ((uint32_t)f2bf(ro) << 16);
}

// ---------------- Flash attention v2 (causal, GQA 4:1) ----------------
// Barrier-free: 4 independent waves per block, each wave owns a 16-row q-chunk
// pair (pi, 127-pi) -> exactly 33 KV tiles per wave (balanced). K read direct
// from global (L2-resident); V read direct from pre-transposed Vt[b][kvh][d][s].
// grid = B * H * 16 = 1024 blocks of 256 threads.
__global__ __launch_bounds__(256) void attn_kernel(const u16* __restrict__ Q,
                                                   const u16* __restrict__ Kc,
                                                   const u16* __restrict__ Vt,
                                                   u16* __restrict__ O) {
  int bid = blockIdx.x;
  int pg = bid & 15, h = (bid >> 4) & 31, b = bid >> 9;
  int kvh = h >> 2;
  int tid = threadIdx.x, lane = tid & 63, w = tid >> 6;
  int l15 = lane & 15, l4 = lane >> 4;
  int pi = pg * 4 + w;  // 0..63 pair index
  __shared__ u16 Ps[4][16][72];  // per-wave P tile [q][kv], stride 72 (16B-aligned rows)
  u16(*myPs)[72] = Ps[w];
  const u16* Qh = Q + (long)b * S_LEN * 2048 + h * 64;
  const u16* Kh = Kc + (long)b * S_LEN * 512 + kvh * 64;
  const u16* Vh = Vt + (long)(b * 8 + kvh) * 64 * S_LEN;
  u16* Oh = O + (long)b * S_LEN * 2048 + h * 64;
#pragma unroll
  for (int half = 0; half < 2; ++half) {
    int c = half ? 127 - pi : pi;  // chunk of 16 q-rows
    int qb = c * 16;
    int nt = (c >> 2) + 1;  // kv tiles of 64
    bf16x8 qf0 = ldfrag(Qh + (long)(qb + l15) * 2048 + l4 * 8);
    bf16x8 qf1 = ldfrag(Qh + (long)(qb + l15) * 2048 + 32 + l4 * 8);
    float m_r[4], l_r[4];
    f32x4 oacc[4] = {};
#pragma unroll
    for (int r = 0; r < 4; ++r) { m_r[r] = -INFINITY; l_r[r] = 0.f; }
    for (int t = 0; t < nt; ++t) {
      int kb = t * 64;
      f32x4 sacc[4] = {};
#pragma unroll
      for (int n = 0; n < 4; ++n) {  // scores S[16q][64kv]
        const u16* kp = Kh + (long)(kb + n * 16 + l15) * 512;
        sacc[n] = mfma16(qf0, ldfrag(kp + l4 * 8), sacc[n]);
        sacc[n] = mfma16(qf1, ldfrag(kp + 32 + l4 * 8), sacc[n]);
      }
      if (t == nt - 1) {  // causal mask (only final tile can cross the diagonal)
#pragma unroll
        for (int n = 0; n < 4; ++n) {
          int kvc = kb + n * 16 + l15;
#pragma unroll
          for (int r = 0; r < 4; ++r)
            if (kvc > qb + l4 * 4 + r) sacc[n][r] = -1e30f;
        }
      }
      float fac[4], rs[4];
#pragma unroll
      for (int r = 0; r < 4; ++r) {
        float mx = fmaxf(fmaxf(sacc[0][r], sacc[1][r]), fmaxf(sacc[2][r], sacc[3][r]));
#pragma unroll
        for (int off = 8; off; off >>= 1) mx = fmaxf(mx, __shfl_xor(mx, off));
        float mn = fmaxf(m_r[r], mx);
        fac[r] = __expf(m_r[r] - mn);
        m_r[r] = mn;
        rs[r] = 0.f;
      }
#pragma unroll
      for (int n = 0; n < 4; ++n)
#pragma unroll
        for (int r = 0; r < 4; ++r) {
          float p = __expf(sacc[n][r] - m_r[r]);
          rs[r] += p;
          myPs[l4 * 4 + r][n * 16 + l15] = f2bf(p);
        }
#pragma unroll
      for (int r = 0; r < 4; ++r) {
        float s = rs[r];
#pragma unroll
        for (int off = 8; off; off >>= 1) s += __shfl_xor(s, off);
        l_r[r] = l_r[r] * fac[r] + s;
      }
#pragma unroll
      for (int f = 0; f < 4; ++f) {
        oacc[f][0] *= fac[0];
        oacc[f][1] *= fac[1];
        oacc[f][2] *= fac[2];
        oacc[f][3] *= fac[3];
      }
      bf16x8 pa0 = ldfrag(&myPs[l15][l4 * 8]);
      bf16x8 pa1 = ldfrag(&myPs[l15][32 + l4 * 8]);
#pragma unroll
      for (int f = 0; f < 4; ++f) {  // O[16q][64d] += P * V, V^T rows from global
        const u16* vp = Vh + (long)(f * 16 + l15) * S_LEN + kb;
        oacc[f] = mfma16(pa0, ldfrag(vp + l4 * 8), oacc[f]);
        oacc[f] = mfma16(pa1, ldfrag(vp + 32 + l4 * 8), oacc[f]);
      }
    }
    float inv[4];
#pragma unroll
    for (int r = 0; r < 4; ++r) inv[r] = 1.f / l_r[r];
#pragma unroll
    for (int f = 0; f < 4; ++f)
#pragma unroll
      for (int r = 0; r < 4; ++r)
        Oh[(long)(qb + l4 * 4 + r) * 2048 + f * 16 + l15] = f2bf(oacc[f][r] * inv[r]);
  }
}

// ---------------- launch ----------------
extern "C" void kernel_launch(void* const* d_in, const int* in_sizes, int n_in,
                              void* d_out, int out_size, void* d_ws, size_t ws_size,
                              hipStream_t stream) {
  const float* x = (const float*)d_in[0];
  const float* Wq = (const float*)d_in[1];
  const float* Wk = (const float*)d_in[2];
  const float* Wv = (const float*)d_in[3];
  const float* Wo = (const float*)d_in[4];
  float* out = (float*)d_out;
  char* ws = (char*)d_ws;
  // workspace layout (bytes)
  u16* xb = (u16*)(ws + 0);          // 4096x2048 bf16   (16 MiB)
  u16* WqT = (u16*)(ws + 16777216);  // 2048x2048        (8 MiB)
  u16* WkT = (u16*)(ws + 25165824);  // 512x2048         (2 MiB)
  u16* WvT = (u16*)(ws + 27262976);  // 512x2048         (2 MiB)
  u16* WoT = (u16*)(ws + 29360128);  // 2048x2048        (8 MiB)
  u16* Qs = (u16*)(ws + 37748736);   // 4096x2048        (16 MiB)
  u16* Ks = (u16*)(ws + 54525952);   // 4096x512         (4 MiB)
  u16* Vt = (u16*)(ws + 58720256);   // [2][8][64][2048] (4 MiB) transposed V
  u16* Os = (u16*)(ws + 62914560);   // 4096x2048        (16 MiB)

  cvt_kernel<<<8192, 256, 0, stream>>>(x, xb, 2097152);
  cvtT_kernel<<<dim3(64, 64), 256, 0, stream>>>(Wq, WqT, 2048, 2048);
  cvtT_kernel<<<dim3(16, 64), 256, 0, stream>>>(Wk, WkT, 2048, 512);
  cvtT_kernel<<<dim3(16, 64), 256, 0, stream>>>(Wv, WvT, 2048, 512);
  cvtT_kernel<<<dim3(64, 64), 256, 0, stream>>>(Wo, WoT, 2048, 2048);
  gemm_bt<1><<<dim3(32, 16), 256, 0, stream>>>(xb, WqT, Qs, 2048, 2048);
  gemm_bt<1><<<dim3(32, 4), 256, 0, stream>>>(xb, WkT, Ks, 2048, 512);
  gemm_bt<2><<<dim3(32, 4), 256, 0, stream>>>(xb, WvT, Vt, 2048, 512);
  rope_kernel<<<16384, 256, 0, stream>>>(Qs, 5, 0.125f, 4194304);  // Q: fold 1/sqrt(64)
  rope_kernel<<<4096, 256, 0, stream>>>(Ks, 3, 1.0f, 1048576);     // K
  attn_kernel<<<1024, 256, 0, stream>>>(Qs, Ks, Vt, Os);
  gemm_bt<0><<<dim3(32, 16), 256, 0, stream>>>(Os, WoT, out, 2048, 2048);
}

// Round 5
// 565.612 us; speedup vs baseline: 1.1723x; 1.1723x over previous
//
#include <hip/hip_runtime.h>
#include <cstdint>

typedef unsigned short u16;
typedef __attribute__((ext_vector_type(8))) __bf16 bf16x8;
typedef __attribute__((ext_vector_type(4))) float f32x4;

#define S_LEN 2048

__device__ __forceinline__ u16 f2bf(float f) {
  uint32_t u = __builtin_bit_cast(uint32_t, f);
  u += 0x7fffu + ((u >> 16) & 1u);
  return (u16)(u >> 16);
}
__device__ __forceinline__ float bf2f(u16 h) {
  return __builtin_bit_cast(float, (uint32_t)h << 16);
}
__device__ __forceinline__ bf16x8 ldfrag(const u16* p) {
  return __builtin_bit_cast(bf16x8, *(const uint4*)p);
}
__device__ __forceinline__ f32x4 mfma16(bf16x8 a, bf16x8 b, f32x4 c) {
  return __builtin_amdgcn_mfma_f32_16x16x32_bf16(a, b, c, 0, 0, 0);
}
// async 16B global -> LDS (dest = wave-uniform base + lane*16)
__device__ __forceinline__ void glds16(const u16* g, u16* l) {
  __builtin_amdgcn_global_load_lds((const __attribute__((address_space(1))) void*)g,
                                   (__attribute__((address_space(3))) void*)l, 16, 0, 0);
}

// ---------------- fp32 -> bf16 convert (vectorized) ----------------
__global__ __launch_bounds__(256) void cvt_kernel(const float* __restrict__ in,
                                                  u16* __restrict__ out, int n4) {
  int i = blockIdx.x * 256 + threadIdx.x;
  if (i >= n4) return;
  float4 v = ((const float4*)in)[i];
  ushort4 o;
  o.x = f2bf(v.x); o.y = f2bf(v.y); o.z = f2bf(v.z); o.w = f2bf(v.w);
  ((ushort4*)out)[i] = o;
}

// ------------- fp32 W[K][N] -> bf16 Wt[N][K] (transpose-convert) -------------
__global__ __launch_bounds__(256) void cvtT_kernel(const float* __restrict__ W,
                                                   u16* __restrict__ Wt, int K, int N) {
  __shared__ float t[32][33];
  int tx = threadIdx.x & 31, ty = threadIdx.x >> 5;  // ty 0..7
  int n0 = blockIdx.x * 32, k0 = blockIdx.y * 32;
#pragma unroll
  for (int j = 0; j < 4; ++j)
    t[ty + 8 * j][tx] = W[(long)(k0 + ty + 8 * j) * N + n0 + tx];
  __syncthreads();
#pragma unroll
  for (int j = 0; j < 4; ++j)
    Wt[(long)(n0 + ty + 8 * j) * K + k0 + tx] = f2bf(t[tx][ty + 8 * j]);
}

// ------------- GEMM: C[M][ldc] = A[M][K](bf16) * Bt[N][K]^T(bf16) -------------
// 128x128 tile, 4 waves (2x2), BK=32, LINEAR LDS [128][32] + global_load_lds x16.
// MODE: 0 = fp32 out, 1 = bf16 out, 2 = bf16 out transposed per-head (Vt[b][kvh][d][s])
template <int MODE>
__global__ __launch_bounds__(256) void gemm_bt(const u16* __restrict__ A,
                                               const u16* __restrict__ Bt,
                                               void* __restrict__ C, int K, int ldc) {
  __shared__ __align__(16) u16 As[128 * 32];
  __shared__ __align__(16) u16 Bs[128 * 32];
  int tid = threadIdx.x;
  int lane = tid & 63, w = tid >> 6;
  int wr = (w >> 1) * 64, wc = (w & 1) * 64;
  int l15 = lane & 15, l4 = lane >> 4;
  int rowbase = blockIdx.x * 128, colbase = blockIdx.y * 128;
  f32x4 acc[4][4] = {};
  // 16B chunk ids: c0 = tid (rows 0..63), c1 = tid + 256 (rows 64..127)
  int r0 = tid >> 2, kc0 = (tid & 3) * 8;
  const u16* Ap0 = A + (long)(rowbase + r0) * K + kc0;
  const u16* Ap1 = A + (long)(rowbase + 64 + r0) * K + kc0;
  const u16* Bp0 = Bt + (long)(colbase + r0) * K + kc0;
  const u16* Bp1 = Bt + (long)(colbase + 64 + r0) * K + kc0;
  u16* Asl0 = As + w * 512;  // wave-uniform LDS bases (64 lanes x 16B = 1KB per wave)
  u16* Asl1 = As + 2048 + w * 512;
  u16* Bsl0 = Bs + w * 512;
  u16* Bsl1 = Bs + 2048 + w * 512;
  for (int k0 = 0; k0 < K; k0 += 32) {
    __syncthreads();
    glds16(Ap0 + k0, Asl0);
    glds16(Ap1 + k0, Asl1);
    glds16(Bp0 + k0, Bsl0);
    glds16(Bp1 + k0, Bsl1);
    __syncthreads();
    bf16x8 af[4], bv[4];
#pragma unroll
    for (int m = 0; m < 4; ++m) af[m] = ldfrag(&As[(wr + m * 16 + l15) * 32 + l4 * 8]);
#pragma unroll
    for (int n = 0; n < 4; ++n) bv[n] = ldfrag(&Bs[(wc + n * 16 + l15) * 32 + l4 * 8]);
#pragma unroll
    for (int m = 0; m < 4; ++m)
#pragma unroll
      for (int n = 0; n < 4; ++n) acc[m][n] = mfma16(af[m], bv[n], acc[m][n]);
  }
#pragma unroll
  for (int m = 0; m < 4; ++m)
#pragma unroll
    for (int n = 0; n < 4; ++n) {
      if (MODE == 2) {
        // Vt[b][kvh][d][s] transposed write: 4 consecutive s per lane -> 8B store
        int row = rowbase + wr + m * 16 + l4 * 4;  // = b*2048 + s, s%4==0
        int col = colbase + wc + n * 16 + l15;     // = kvh*64 + d
        int b_ = row >> 11, s_ = row & 2047;
        int kvh_ = col >> 6, d_ = col & 63;
        ushort4 pk;
        pk.x = f2bf(acc[m][n][0]); pk.y = f2bf(acc[m][n][1]);
        pk.z = f2bf(acc[m][n][2]); pk.w = f2bf(acc[m][n][3]);
        *(ushort4*)&((u16*)C)[((long)((b_ * 8 + kvh_) * 64 + d_)) * 2048 + s_] = pk;
      } else {
#pragma unroll
        for (int r = 0; r < 4; ++r) {
          int row = rowbase + wr + m * 16 + l4 * 4 + r;
          int col = colbase + wc + n * 16 + l15;
          if (MODE == 1)
            ((u16*)C)[(long)row * ldc + col] = f2bf(acc[m][n][r]);
          else
            ((float*)C)[(long)row * ldc + col] = acc[m][n][r];
        }
      }
    }
}

// ---------------- RoPE (interleaved pairs), optional score-scale fold ----------------
__global__ __launch_bounds__(256) void rope_kernel(u16* __restrict__ T, int log2H,
                                                   float scale, int total) {
  int p = blockIdx.x * 256 + threadIdx.x;
  if (p >= total) return;
  int i = p & 31;
  int s = (p >> (5 + log2H)) & (S_LEN - 1);
  float freq = exp2f(-(float)i * (13.287712379549449f / 32.0f));  // theta^(-i/32)
  float ang = (float)s * freq;
  float sn, cs;
  sincosf(ang, &sn, &cs);
  uint32_t v = ((uint32_t*)T)[p];
  float e = bf2f((u16)(v & 0xffff)), o = bf2f((u16)(v >> 16));
  float re = (e * cs - o * sn) * scale;
  float ro = (e * sn + o * cs) * scale;
  ((uint32_t*)T)[p] = (uint32_t)f2bf(re) | ((uint32_t)f2bf(ro) << 16);
}

// ---------------- Flash attention v3 (causal, GQA 4:1, swapped QK^T) ----------------
// Barrier-free: 4 independent waves/block, wave owns chunk pair (pi, 127-pi).
// Swapped scores: sacc = mfma(K, Q) -> S[k][q], col=q=l15 => softmax state is
// per-lane scalar; 4 shuffles + 4x8B LDS writes per tile (vs 32 shfl + 16x2B).
// K tile register-prefetched one tile ahead. V from pre-transposed Vt[b][kvh][d][s].
__global__ __launch_bounds__(256) void attn_kernel(const u16* __restrict__ Q,
                                                   const u16* __restrict__ Kc,
                                                   const u16* __restrict__ Vt,
                                                   u16* __restrict__ O) {
  int bid = blockIdx.x;
  int pg = bid & 15, h = (bid >> 4) & 31, b = bid >> 9;
  int kvh = h >> 2;
  int tid = threadIdx.x, lane = tid & 63, w = tid >> 6;
  int l15 = lane & 15, l4 = lane >> 4;
  int pi = pg * 4 + w;  // 0..63 pair index
  __shared__ u16 Ps[4][16][72];  // per-wave P^T tile [q][k], stride 72
  u16(*myPs)[72] = Ps[w];
  const u16* Qh = Q + (long)b * S_LEN * 2048 + h * 64;
  const u16* Kh = Kc + (long)b * S_LEN * 512 + kvh * 64;
  const u16* Vh = Vt + (long)(b * 8 + kvh) * 64 * S_LEN;
  u16* Oh = O + (long)b * S_LEN * 2048 + h * 64;
#pragma unroll
  for (int half = 0; half < 2; ++half) {
    int c = half ? 127 - pi : pi;  // chunk of 16 q-rows
    int qb = c * 16;
    int nt = (c >> 2) + 1;  // kv tiles of 64
    bf16x8 qf0 = ldfrag(Qh + (long)(qb + l15) * 2048 + l4 * 8);
    bf16x8 qf1 = ldfrag(Qh + (long)(qb + l15) * 2048 + 32 + l4 * 8);
    float m_r = -INFINITY, l_r = 0.f;
    f32x4 oacc[4] = {};
    bf16x8 kf[8];
#pragma unroll
    for (int n = 0; n < 4; ++n) {  // preload K tile 0
      const u16* kp = Kh + (long)(n * 16 + l15) * 512;
      kf[2 * n] = ldfrag(kp + l4 * 8);
      kf[2 * n + 1] = ldfrag(kp + 32 + l4 * 8);
    }
    for (int t = 0; t < nt; ++t) {
      int kb = t * 64;
      f32x4 sacc[4] = {};
#pragma unroll
      for (int n = 0; n < 4; ++n) {  // S^T[64k][16q]
        sacc[n] = mfma16(kf[2 * n], qf0, sacc[n]);
        sacc[n] = mfma16(kf[2 * n + 1], qf1, sacc[n]);
      }
      if (t + 1 < nt) {  // prefetch next K tile (hides L2 latency under softmax/PV)
#pragma unroll
        for (int n = 0; n < 4; ++n) {
          const u16* kp = Kh + (long)(kb + 64 + n * 16 + l15) * 512;
          kf[2 * n] = ldfrag(kp + l4 * 8);
          kf[2 * n + 1] = ldfrag(kp + 32 + l4 * 8);
        }
      }
      if (t == nt - 1) {  // causal mask: k = kb+n*16+l4*4+r, q = qb+l15
#pragma unroll
        for (int n = 0; n < 4; ++n) {
          int kc_ = kb + n * 16 + l4 * 4;
#pragma unroll
          for (int r = 0; r < 4; ++r)
            if (kc_ + r > qb + l15) sacc[n][r] = -1e30f;
        }
      }
      // per-lane max over 16 owned scores, then reduce across l4 groups
      float mx = fmaxf(fmaxf(fmaxf(sacc[0][0], sacc[0][1]), fmaxf(sacc[0][2], sacc[0][3])),
                       fmaxf(fmaxf(sacc[1][0], sacc[1][1]), fmaxf(sacc[1][2], sacc[1][3])));
      mx = fmaxf(mx, fmaxf(fmaxf(fmaxf(sacc[2][0], sacc[2][1]), fmaxf(sacc[2][2], sacc[2][3])),
                           fmaxf(fmaxf(sacc[3][0], sacc[3][1]), fmaxf(sacc[3][2], sacc[3][3]))));
      mx = fmaxf(mx, __shfl_xor(mx, 16));
      mx = fmaxf(mx, __shfl_xor(mx, 32));
      float mn = fmaxf(m_r, mx);
      float fac = __expf(m_r - mn);
      m_r = mn;
      float rs = 0.f;
#pragma unroll
      for (int n = 0; n < 4; ++n) {
        float p0 = __expf(sacc[n][0] - mn);
        float p1 = __expf(sacc[n][1] - mn);
        float p2 = __expf(sacc[n][2] - mn);
        float p3 = __expf(sacc[n][3] - mn);
        rs += (p0 + p1) + (p2 + p3);
        ushort4 pk;
        pk.x = f2bf(p0); pk.y = f2bf(p1); pk.z = f2bf(p2); pk.w = f2bf(p3);
        *(ushort4*)&myPs[l15][n * 16 + l4 * 4] = pk;  // 8B write, 2-way alias (free)
      }
      rs += __shfl_xor(rs, 16);
      rs += __shfl_xor(rs, 32);
      l_r = l_r * fac + rs;
      // rescale O: fac for output q-row l4*4+r lives in lane with l15 == that row
      float facq[4];
#pragma unroll
      for (int r = 0; r < 4; ++r) facq[r] = __shfl(fac, (lane & 48) | (l4 * 4 + r));
#pragma unroll
      for (int f = 0; f < 4; ++f) {
        oacc[f][0] *= facq[0];
        oacc[f][1] *= facq[1];
        oacc[f][2] *= facq[2];
        oacc[f][3] *= facq[3];
      }
      bf16x8 pa0 = ldfrag(&myPs[l15][l4 * 8]);
      bf16x8 pa1 = ldfrag(&myPs[l15][32 + l4 * 8]);
#pragma unroll
      for (int f = 0; f < 4; ++f) {  // O[16q][64d] += P * V
        const u16* vp = Vh + (long)(f * 16 + l15) * S_LEN + kb;
        oacc[f] = mfma16(pa0, ldfrag(vp + l4 * 8), oacc[f]);
        oacc[f] = mfma16(pa1, ldfrag(vp + 32 + l4 * 8), oacc[f]);
      }
    }
    float linv = 1.f / l_r;
    float invq[4];
#pragma unroll
    for (int r = 0; r < 4; ++r) invq[r] = __shfl(linv, (lane & 48) | (l4 * 4 + r));
#pragma unroll
    for (int f = 0; f < 4; ++f)
#pragma unroll
      for (int r = 0; r < 4; ++r)
        Oh[(long)(qb + l4 * 4 + r) * 2048 + f * 16 + l15] = f2bf(oacc[f][r] * invq[r]);
  }
}

// ---------------- launch ----------------
extern "C" void kernel_launch(void* const* d_in, const int* in_sizes, int n_in,
                              void* d_out, int out_size, void* d_ws, size_t ws_size,
                              hipStream_t stream) {
  const float* x = (const float*)d_in[0];
  const float* Wq = (const float*)d_in[1];
  const float* Wk = (const float*)d_in[2];
  const float* Wv = (const float*)d_in[3];
  const float* Wo = (const float*)d_in[4];
  float* out = (float*)d_out;
  char* ws = (char*)d_ws;
  // workspace layout (bytes)
  u16* xb = (u16*)(ws + 0);          // 4096x2048 bf16   (16 MiB)
  u16* WqT = (u16*)(ws + 16777216);  // 2048x2048        (8 MiB)
  u16* WkT = (u16*)(ws + 25165824);  // 512x2048         (2 MiB)
  u16* WvT = (u16*)(ws + 27262976);  // 512x2048         (2 MiB)
  u16* WoT = (u16*)(ws + 29360128);  // 2048x2048        (8 MiB)
  u16* Qs = (u16*)(ws + 37748736);   // 4096x2048        (16 MiB)
  u16* Ks = (u16*)(ws + 54525952);   // 4096x512         (4 MiB)
  u16* Vt = (u16*)(ws + 58720256);   // [2][8][64][2048] (4 MiB) transposed V
  u16* Os = (u16*)(ws + 62914560);   // 4096x2048        (16 MiB)

  cvt_kernel<<<8192, 256, 0, stream>>>(x, xb, 2097152);
  cvtT_kernel<<<dim3(64, 64), 256, 0, stream>>>(Wq, WqT, 2048, 2048);
  cvtT_kernel<<<dim3(16, 64), 256, 0, stream>>>(Wk, WkT, 2048, 512);
  cvtT_kernel<<<dim3(16, 64), 256, 0, stream>>>(Wv, WvT, 2048, 512);
  cvtT_kernel<<<dim3(64, 64), 256, 0, stream>>>(Wo, WoT, 2048, 2048);
  gemm_bt<1><<<dim3(32, 16), 256, 0, stream>>>(xb, WqT, Qs, 2048, 2048);
  gemm_bt<1><<<dim3(32, 4), 256, 0, stream>>>(xb, WkT, Ks, 2048, 512);
  gemm_bt<2><<<dim3(32, 4), 256, 0, stream>>>(xb, WvT, Vt, 2048, 512);
  rope_kernel<<<16384, 256, 0, stream>>>(Qs, 5, 0.125f, 4194304);  // Q: fold 1/sqrt(64)
  rope_kernel<<<4096, 256, 0, stream>>>(Ks, 3, 1.0f, 1048576);     // K
  attn_kernel<<<1024, 256, 0, stream>>>(Qs, Ks, Vt, Os);
  gemm_bt<0><<<dim3(32, 16), 256, 0, stream>>>(Os, WoT, out, 2048, 2048);
}

// Round 6
// 557.991 us; speedup vs baseline: 1.1883x; 1.0137x over previous
//
#include <hip/hip_runtime.h>
#include <cstdint>

typedef unsigned short u16;
typedef __attribute__((ext_vector_type(8))) __bf16 bf16x8;
typedef __attribute__((ext_vector_type(4))) float f32x4;

#define S_LEN 2048

__device__ __forceinline__ u16 f2bf(float f) {
  uint32_t u = __builtin_bit_cast(uint32_t, f);
  u += 0x7fffu + ((u >> 16) & 1u);
  return (u16)(u >> 16);
}
__device__ __forceinline__ float bf2f(u16 h) {
  return __builtin_bit_cast(float, (uint32_t)h << 16);
}
__device__ __forceinline__ bf16x8 ldfrag(const u16* p) {
  return __builtin_bit_cast(bf16x8, *(const uint4*)p);
}
__device__ __forceinline__ f32x4 mfma16(bf16x8 a, bf16x8 b, f32x4 c) {
  return __builtin_amdgcn_mfma_f32_16x16x32_bf16(a, b, c, 0, 0, 0);
}
// async 16B global -> LDS (dest = wave-uniform base + lane*16)
__device__ __forceinline__ void glds16(const u16* g, u16* l) {
  __builtin_amdgcn_global_load_lds((const __attribute__((address_space(1))) void*)g,
                                   (__attribute__((address_space(3))) void*)l, 16, 0, 0);
}

// ---------------- fp32 -> bf16 convert (vectorized) ----------------
__global__ __launch_bounds__(256) void cvt_kernel(const float* __restrict__ in,
                                                  u16* __restrict__ out, int n4) {
  int i = blockIdx.x * 256 + threadIdx.x;
  if (i >= n4) return;
  float4 v = ((const float4*)in)[i];
  ushort4 o;
  o.x = f2bf(v.x); o.y = f2bf(v.y); o.z = f2bf(v.z); o.w = f2bf(v.w);
  ((ushort4*)out)[i] = o;
}

// ------------- fp32 W[K][N] -> bf16 Wt[N][K] (transpose-convert) -------------
__global__ __launch_bounds__(256) void cvtT_kernel(const float* __restrict__ W,
                                                   u16* __restrict__ Wt, int K, int N) {
  __shared__ float t[32][33];
  int tx = threadIdx.x & 31, ty = threadIdx.x >> 5;  // ty 0..7
  int n0 = blockIdx.x * 32, k0 = blockIdx.y * 32;
#pragma unroll
  for (int j = 0; j < 4; ++j)
    t[ty + 8 * j][tx] = W[(long)(k0 + ty + 8 * j) * N + n0 + tx];
  __syncthreads();
#pragma unroll
  for (int j = 0; j < 4; ++j)
    Wt[(long)(n0 + ty + 8 * j) * K + k0 + tx] = f2bf(t[tx][ty + 8 * j]);
}

// ------------- GEMM: C[M][ldc] = A[M][K](bf16) * Bt[N][K]^T(bf16) -------------
// 128x128 tile, 4 waves (2x2), BK=32, LINEAR LDS [128][32] + global_load_lds x16.
// MODE: 0 = fp32 out, 1 = bf16 out, 2 = bf16 out transposed per-head (Vt[b][kvh][d][s])
template <int MODE>
__global__ __launch_bounds__(256) void gemm_bt(const u16* __restrict__ A,
                                               const u16* __restrict__ Bt,
                                               void* __restrict__ C, int K, int ldc) {
  __shared__ __align__(16) u16 As[128 * 32];
  __shared__ __align__(16) u16 Bs[128 * 32];
  int tid = threadIdx.x;
  int lane = tid & 63, w = tid >> 6;
  int wr = (w >> 1) * 64, wc = (w & 1) * 64;
  int l15 = lane & 15, l4 = lane >> 4;
  int rowbase = blockIdx.x * 128, colbase = blockIdx.y * 128;
  f32x4 acc[4][4] = {};
  int r0 = tid >> 2, kc0 = (tid & 3) * 8;
  const u16* Ap0 = A + (long)(rowbase + r0) * K + kc0;
  const u16* Ap1 = A + (long)(rowbase + 64 + r0) * K + kc0;
  const u16* Bp0 = Bt + (long)(colbase + r0) * K + kc0;
  const u16* Bp1 = Bt + (long)(colbase + 64 + r0) * K + kc0;
  u16* Asl0 = As + w * 512;  // wave-uniform LDS bases (64 lanes x 16B = 1KB per wave)
  u16* Asl1 = As + 2048 + w * 512;
  u16* Bsl0 = Bs + w * 512;
  u16* Bsl1 = Bs + 2048 + w * 512;
  for (int k0 = 0; k0 < K; k0 += 32) {
    __syncthreads();
    glds16(Ap0 + k0, Asl0);
    glds16(Ap1 + k0, Asl1);
    glds16(Bp0 + k0, Bsl0);
    glds16(Bp1 + k0, Bsl1);
    __syncthreads();
    bf16x8 af[4], bv[4];
#pragma unroll
    for (int m = 0; m < 4; ++m) af[m] = ldfrag(&As[(wr + m * 16 + l15) * 32 + l4 * 8]);
#pragma unroll
    for (int n = 0; n < 4; ++n) bv[n] = ldfrag(&Bs[(wc + n * 16 + l15) * 32 + l4 * 8]);
#pragma unroll
    for (int m = 0; m < 4; ++m)
#pragma unroll
      for (int n = 0; n < 4; ++n) acc[m][n] = mfma16(af[m], bv[n], acc[m][n]);
  }
#pragma unroll
  for (int m = 0; m < 4; ++m)
#pragma unroll
    for (int n = 0; n < 4; ++n) {
      if (MODE == 2) {
        // Vt[b][kvh][d][s] transposed write: 4 consecutive s per lane -> 8B store
        int row = rowbase + wr + m * 16 + l4 * 4;  // = b*2048 + s, s%4==0
        int col = colbase + wc + n * 16 + l15;     // = kvh*64 + d
        int b_ = row >> 11, s_ = row & 2047;
        int kvh_ = col >> 6, d_ = col & 63;
        ushort4 pk;
        pk.x = f2bf(acc[m][n][0]); pk.y = f2bf(acc[m][n][1]);
        pk.z = f2bf(acc[m][n][2]); pk.w = f2bf(acc[m][n][3]);
        *(ushort4*)&((u16*)C)[((long)((b_ * 8 + kvh_) * 64 + d_)) * 2048 + s_] = pk;
      } else {
#pragma unroll
        for (int r = 0; r < 4; ++r) {
          int row = rowbase + wr + m * 16 + l4 * 4 + r;
          int col = colbase + wc + n * 16 + l15;
          if (MODE == 1)
            ((u16*)C)[(long)row * ldc + col] = f2bf(acc[m][n][r]);
          else
            ((float*)C)[(long)row * ldc + col] = acc[m][n][r];
        }
      }
    }
}

// ---------------- RoPE cos/sin table: ctab[s*32+i] = {cos,sin}(s * theta^(-i/32)) ----------------
__global__ __launch_bounds__(256) void rope_tab_kernel(float2* __restrict__ ctab) {
  int idx = blockIdx.x * 256 + threadIdx.x;  // 65536 = 2048 s x 32 i
  int i = idx & 31, s = idx >> 5;
  float freq = exp2f(-(float)i * (13.287712379549449f / 32.0f));
  float sn, cs;
  sincosf((float)s * freq, &sn, &cs);
  ctab[idx] = make_float2(cs, sn);
}

// ---------------- RoPE for K (table-driven, in place) ----------------
__global__ __launch_bounds__(256) void ropeK_kernel(u16* __restrict__ T,
                                                    const float2* __restrict__ ctab) {
  int p = blockIdx.x * 256 + threadIdx.x;  // 1048576 uint32 pairs
  int i = p & 31;
  int s = (p >> 8) & (S_LEN - 1);
  float2 cs = ctab[s * 32 + i];
  uint32_t v = ((uint32_t*)T)[p];
  float e = bf2f((u16)(v & 0xffff)), o = bf2f((u16)(v >> 16));
  float re = e * cs.x - o * cs.y;
  float ro = e * cs.y + o * cs.x;
  ((uint32_t*)T)[p] = (uint32_t)f2bf(re) | ((uint32_t)f2bf(ro) << 16);
}

// ---------------- Flash attention v4 (causal, GQA 4:1, all-swapped) ----------------
// One 16-row q-chunk per wave; 2048 blocks x 4 waves = 8 waves/SIMD max occupancy.
// Block p waves own chunks {2p, 2p+1, 127-2p, 126-2p} (66 tiles/block, exactly
// balanced), rotated across wave slots so each SIMD mixes long/short waves.
// Swapped scores S^T = mfma(K,Q) AND swapped output O^T = mfma(V^T, P^T):
// softmax state m,l and rescale factors are per-lane scalars (q = lane&15) --
// zero broadcast shuffles. RoPE applied to Q at load (table). V from Vt[b][kvh][d][s].
__global__ __launch_bounds__(256, 8) void attn_kernel(const u16* __restrict__ Q,
                                                      const u16* __restrict__ Kc,
                                                      const u16* __restrict__ Vt,
                                                      const float2* __restrict__ ctab,
                                                      u16* __restrict__ O) {
  int bid = blockIdx.x;
  int p = bid & 31, h = (bid >> 5) & 31, b = bid >> 10;
  int kvh = h >> 2;
  int tid = threadIdx.x, lane = tid & 63, w = tid >> 6;
  int l15 = lane & 15, l4 = lane >> 4;
  int cc = (w + p) & 3;  // rotate chunk->wave-slot so SIMDs mix lengths
  int c = cc == 0 ? 2 * p : cc == 1 ? 2 * p + 1 : cc == 2 ? 127 - 2 * p : 126 - 2 * p;
  int qb = c * 16;
  int nt = (c >> 2) + 1;  // kv tiles of 64
  __shared__ u16 Ps[4][16][72];  // per-wave P tile [q][k], stride 72
  u16(*myPs)[72] = Ps[w];
  const u16* Qh = Q + (long)b * S_LEN * 2048 + h * 64;
  const u16* Kh = Kc + (long)b * S_LEN * 512 + kvh * 64;
  const u16* Vh = Vt + (long)(b * 8 + kvh) * 64 * S_LEN;
  u16* Oh = O + (long)b * S_LEN * 2048 + h * 64;
  // ---- load Q row (q = qb+l15) and apply RoPE in-register (scale folds 1/sqrt(64))
  int s = qb + l15;
  const u16* qp = Qh + (long)s * 2048;
  uint4 r0 = *(const uint4*)(qp + l4 * 8);       // pairs i = l4*4 + jj
  uint4 r1 = *(const uint4*)(qp + 32 + l4 * 8);  // pairs i = 16 + l4*4 + jj
  const float2* ct = ctab + (long)s * 32 + l4 * 4;
  uint32_t q0w[4], q1w[4];
#pragma unroll
  for (int jj = 0; jj < 4; ++jj) {
    float2 cs0 = ct[jj], cs1 = ct[16 + jj];
    uint32_t v0 = ((const uint32_t*)&r0)[jj], v1 = ((const uint32_t*)&r1)[jj];
    float e0 = bf2f((u16)v0), o0 = bf2f((u16)(v0 >> 16));
    float e1 = bf2f((u16)v1), o1 = bf2f((u16)(v1 >> 16));
    float a0 = (e0 * cs0.x - o0 * cs0.y) * 0.125f;
    float b0 = (e0 * cs0.y + o0 * cs0.x) * 0.125f;
    float a1 = (e1 * cs1.x - o1 * cs1.y) * 0.125f;
    float b1 = (e1 * cs1.y + o1 * cs1.x) * 0.125f;
    q0w[jj] = (uint32_t)f2bf(a0) | ((uint32_t)f2bf(b0) << 16);
    q1w[jj] = (uint32_t)f2bf(a1) | ((uint32_t)f2bf(b1) << 16);
  }
  bf16x8 qf0 = __builtin_bit_cast(bf16x8, *(uint4*)q0w);
  bf16x8 qf1 = __builtin_bit_cast(bf16x8, *(uint4*)q1w);
  float m_r = -INFINITY, l_r = 0.f;
  f32x4 oaccT[4] = {};
  for (int t = 0; t < nt; ++t) {
    int kb = t * 64;
    f32x4 sacc[4] = {};
#pragma unroll
    for (int n = 0; n < 4; ++n) {  // S^T[64k][16q]
      const u16* kp = Kh + (long)(kb + n * 16 + l15) * 512;
      sacc[n] = mfma16(ldfrag(kp + l4 * 8), qf0, sacc[n]);
      sacc[n] = mfma16(ldfrag(kp + 32 + l4 * 8), qf1, sacc[n]);
    }
    if (t == nt - 1) {  // causal mask: k = kb+n*16+l4*4+r, q = qb+l15
#pragma unroll
      for (int n = 0; n < 4; ++n) {
        int kc_ = kb + n * 16 + l4 * 4;
#pragma unroll
        for (int r = 0; r < 4; ++r)
          if (kc_ + r > qb + l15) sacc[n][r] = -1e30f;
      }
    }
    // per-lane max over the 16 owned k-scores (same q), then across l4 groups
    float mx = fmaxf(fmaxf(fmaxf(sacc[0][0], sacc[0][1]), fmaxf(sacc[0][2], sacc[0][3])),
                     fmaxf(fmaxf(sacc[1][0], sacc[1][1]), fmaxf(sacc[1][2], sacc[1][3])));
    mx = fmaxf(mx, fmaxf(fmaxf(fmaxf(sacc[2][0], sacc[2][1]), fmaxf(sacc[2][2], sacc[2][3])),
                         fmaxf(fmaxf(sacc[3][0], sacc[3][1]), fmaxf(sacc[3][2], sacc[3][3]))));
    mx = fmaxf(mx, __shfl_xor(mx, 16));
    mx = fmaxf(mx, __shfl_xor(mx, 32));
    float mn = fmaxf(m_r, mx);
    float fac = __expf(m_r - mn);
    m_r = mn;
    float rs = 0.f;
#pragma unroll
    for (int n = 0; n < 4; ++n) {
      float p0 = __expf(sacc[n][0] - mn);
      float p1 = __expf(sacc[n][1] - mn);
      float p2 = __expf(sacc[n][2] - mn);
      float p3 = __expf(sacc[n][3] - mn);
      rs += (p0 + p1) + (p2 + p3);
      ushort4 pk;
      pk.x = f2bf(p0); pk.y = f2bf(p1); pk.z = f2bf(p2); pk.w = f2bf(p3);
      *(ushort4*)&myPs[l15][n * 16 + l4 * 4] = pk;
    }
    rs += __shfl_xor(rs, 16);
    rs += __shfl_xor(rs, 32);
    l_r = l_r * fac + rs;
#pragma unroll
    for (int f = 0; f < 4; ++f) {  // O^T rescale: per-lane fac (q = l15)
      oaccT[f][0] *= fac; oaccT[f][1] *= fac;
      oaccT[f][2] *= fac; oaccT[f][3] *= fac;
    }
    bf16x8 pa0 = ldfrag(&myPs[l15][l4 * 8]);
    bf16x8 pa1 = ldfrag(&myPs[l15][32 + l4 * 8]);
#pragma unroll
    for (int f = 0; f < 4; ++f) {  // O^T[64d][16q] += V^T * P^T
      const u16* vp = Vh + (long)(f * 16 + l15) * S_LEN + kb;
      oaccT[f] = mfma16(ldfrag(vp + l4 * 8), pa0, oaccT[f]);
      oaccT[f] = mfma16(ldfrag(vp + 32 + l4 * 8), pa1, oaccT[f]);
    }
  }
  float linv = 1.f / l_r;  // per-lane (q = l15)
#pragma unroll
  for (int f = 0; f < 4; ++f) {
    ushort4 pk;
    pk.x = f2bf(oaccT[f][0] * linv); pk.y = f2bf(oaccT[f][1] * linv);
    pk.z = f2bf(oaccT[f][2] * linv); pk.w = f2bf(oaccT[f][3] * linv);
    *(ushort4*)&Oh[(long)(qb + l15) * 2048 + f * 16 + l4 * 4] = pk;  // 8B store
  }
}

// ---------------- launch ----------------
extern "C" void kernel_launch(void* const* d_in, const int* in_sizes, int n_in,
                              void* d_out, int out_size, void* d_ws, size_t ws_size,
                              hipStream_t stream) {
  const float* x = (const float*)d_in[0];
  const float* Wq = (const float*)d_in[1];
  const float* Wk = (const float*)d_in[2];
  const float* Wv = (const float*)d_in[3];
  const float* Wo = (const float*)d_in[4];
  float* out = (float*)d_out;
  char* ws = (char*)d_ws;
  // workspace layout (bytes)
  u16* xb = (u16*)(ws + 0);          // 4096x2048 bf16   (16 MiB)
  u16* WqT = (u16*)(ws + 16777216);  // 2048x2048        (8 MiB)
  u16* WkT = (u16*)(ws + 25165824);  // 512x2048         (2 MiB)
  u16* WvT = (u16*)(ws + 27262976);  // 512x2048         (2 MiB)
  u16* WoT = (u16*)(ws + 29360128);  // 2048x2048        (8 MiB)
  u16* Qs = (u16*)(ws + 37748736);   // 4096x2048        (16 MiB)
  u16* Ks = (u16*)(ws + 54525952);   // 4096x512         (4 MiB)
  u16* Vt = (u16*)(ws + 58720256);   // [2][8][64][2048] (4 MiB) transposed V
  u16* Os = (u16*)(ws + 62914560);   // 4096x2048        (16 MiB)
  float2* ctab = (float2*)(ws + 79691776);  // 2048x32 cos/sin (512 KiB)

  cvt_kernel<<<8192, 256, 0, stream>>>(x, xb, 2097152);
  cvtT_kernel<<<dim3(64, 64), 256, 0, stream>>>(Wq, WqT, 2048, 2048);
  cvtT_kernel<<<dim3(16, 64), 256, 0, stream>>>(Wk, WkT, 2048, 512);
  cvtT_kernel<<<dim3(16, 64), 256, 0, stream>>>(Wv, WvT, 2048, 512);
  cvtT_kernel<<<dim3(64, 64), 256, 0, stream>>>(Wo, WoT, 2048, 2048);
  rope_tab_kernel<<<256, 256, 0, stream>>>(ctab);
  gemm_bt<1><<<dim3(32, 16), 256, 0, stream>>>(xb, WqT, Qs, 2048, 2048);
  gemm_bt<1><<<dim3(32, 4), 256, 0, stream>>>(xb, WkT, Ks, 2048, 512);
  gemm_bt<2><<<dim3(32, 4), 256, 0, stream>>>(xb, WvT, Vt, 2048, 512);
  ropeK_kernel<<<4096, 256, 0, stream>>>(Ks, ctab);
  attn_kernel<<<2048, 256, 0, stream>>>(Qs, Ks, Vt, ctab, Os);
  gemm_bt<0><<<dim3(32, 16), 256, 0, stream>>>(Os, WoT, out, 2048, 2048);
}

// Round 8
// 451.951 us; speedup vs baseline: 1.4671x; 1.2346x over previous
//
#include <hip/hip_runtime.h>
#include <cstdint>

typedef unsigned short u16;
typedef __attribute__((ext_vector_type(8))) __bf16 bf16x8;
typedef __attribute__((ext_vector_type(4))) float f32x4;

#define S_LEN 2048

__device__ __forceinline__ u16 f2bf(float f) {
  uint32_t u = __builtin_bit_cast(uint32_t, f);
  u += 0x7fffu + ((u >> 16) & 1u);
  return (u16)(u >> 16);
}
__device__ __forceinline__ float bf2f(u16 h) {
  return __builtin_bit_cast(float, (uint32_t)h << 16);
}
__device__ __forceinline__ bf16x8 ldfrag(const u16* p) {
  return __builtin_bit_cast(bf16x8, *(const uint4*)p);
}
__device__ __forceinline__ f32x4 mfma16(bf16x8 a, bf16x8 b, f32x4 c) {
  return __builtin_amdgcn_mfma_f32_16x16x32_bf16(a, b, c, 0, 0, 0);
}
// async 16B global -> LDS (dest = wave-uniform base + lane*16)
__device__ __forceinline__ void glds16(const u16* g, u16* l) {
  __builtin_amdgcn_global_load_lds((const __attribute__((address_space(1))) void*)g,
                                   (__attribute__((address_space(3))) void*)l, 16, 0, 0);
}

// ---------------- fp32 -> bf16 convert (vectorized) ----------------
__global__ __launch_bounds__(256) void cvt_kernel(const float* __restrict__ in,
                                                  u16* __restrict__ out, int n4) {
  int i = blockIdx.x * 256 + threadIdx.x;
  if (i >= n4) return;
  float4 v = ((const float4*)in)[i];
  ushort4 o;
  o.x = f2bf(v.x); o.y = f2bf(v.y); o.z = f2bf(v.z); o.w = f2bf(v.w);
  ((ushort4*)out)[i] = o;
}

// ------------- fp32 W[K][N] -> bf16 Wt[N][K] (transpose-convert) -------------
__global__ __launch_bounds__(256) void cvtT_kernel(const float* __restrict__ W,
                                                   u16* __restrict__ Wt, int K, int N) {
  __shared__ float t[32][33];
  int tx = threadIdx.x & 31, ty = threadIdx.x >> 5;  // ty 0..7
  int n0 = blockIdx.x * 32, k0 = blockIdx.y * 32;
#pragma unroll
  for (int j = 0; j < 4; ++j)
    t[ty + 8 * j][tx] = W[(long)(k0 + ty + 8 * j) * N + n0 + tx];
  __syncthreads();
#pragma unroll
  for (int j = 0; j < 4; ++j)
    Wt[(long)(n0 + ty + 8 * j) * K + k0 + tx] = f2bf(t[tx][ty + 8 * j]);
}

// ------------- GEMM: C[M][ldc] = A[M][K](bf16) * Bt[N][K]^T(bf16) -------------
// 128x128 tile, 4 waves (2x2), BK=32, LINEAR LDS [128][32] + global_load_lds x16.
// MODE: 0 = fp32 out, 1 = bf16 out, 2 = bf16 out transposed per-head (Vt[b][kvh][d][s])
template <int MODE>
__global__ __launch_bounds__(256) void gemm_bt(const u16* __restrict__ A,
                                               const u16* __restrict__ Bt,
                                               void* __restrict__ C, int K, int ldc) {
  __shared__ __align__(16) u16 As[128 * 32];
  __shared__ __align__(16) u16 Bs[128 * 32];
  int tid = threadIdx.x;
  int lane = tid & 63, w = tid >> 6;
  int wr = (w >> 1) * 64, wc = (w & 1) * 64;
  int l15 = lane & 15, l4 = lane >> 4;
  int rowbase = blockIdx.x * 128, colbase = blockIdx.y * 128;
  f32x4 acc[4][4] = {};
  int r0 = tid >> 2, kc0 = (tid & 3) * 8;
  const u16* Ap0 = A + (long)(rowbase + r0) * K + kc0;
  const u16* Ap1 = A + (long)(rowbase + 64 + r0) * K + kc0;
  const u16* Bp0 = Bt + (long)(colbase + r0) * K + kc0;
  const u16* Bp1 = Bt + (long)(colbase + 64 + r0) * K + kc0;
  u16* Asl0 = As + w * 512;  // wave-uniform LDS bases (64 lanes x 16B = 1KB per wave)
  u16* Asl1 = As + 2048 + w * 512;
  u16* Bsl0 = Bs + w * 512;
  u16* Bsl1 = Bs + 2048 + w * 512;
  for (int k0 = 0; k0 < K; k0 += 32) {
    __syncthreads();
    glds16(Ap0 + k0, Asl0);
    glds16(Ap1 + k0, Asl1);
    glds16(Bp0 + k0, Bsl0);
    glds16(Bp1 + k0, Bsl1);
    __syncthreads();
    bf16x8 af[4], bv[4];
#pragma unroll
    for (int m = 0; m < 4; ++m) af[m] = ldfrag(&As[(wr + m * 16 + l15) * 32 + l4 * 8]);
#pragma unroll
    for (int n = 0; n < 4; ++n) bv[n] = ldfrag(&Bs[(wc + n * 16 + l15) * 32 + l4 * 8]);
#pragma unroll
    for (int m = 0; m < 4; ++m)
#pragma unroll
      for (int n = 0; n < 4; ++n) acc[m][n] = mfma16(af[m], bv[n], acc[m][n]);
  }
#pragma unroll
  for (int m = 0; m < 4; ++m)
#pragma unroll
    for (int n = 0; n < 4; ++n) {
      if (MODE == 2) {
        // Vt[b][kvh][d][s] transposed write: 4 consecutive s per lane -> 8B store
        int row = rowbase + wr + m * 16 + l4 * 4;  // = b*2048 + s, s%4==0
        int col = colbase + wc + n * 16 + l15;     // = kvh*64 + d
        int b_ = row >> 11, s_ = row & 2047;
        int kvh_ = col >> 6, d_ = col & 63;
        ushort4 pk;
        pk.x = f2bf(acc[m][n][0]); pk.y = f2bf(acc[m][n][1]);
        pk.z = f2bf(acc[m][n][2]); pk.w = f2bf(acc[m][n][3]);
        *(ushort4*)&((u16*)C)[((long)((b_ * 8 + kvh_) * 64 + d_)) * 2048 + s_] = pk;
      } else {
#pragma unroll
        for (int r = 0; r < 4; ++r) {
          int row = rowbase + wr + m * 16 + l4 * 4 + r;
          int col = colbase + wc + n * 16 + l15;
          if (MODE == 1)
            ((u16*)C)[(long)row * ldc + col] = f2bf(acc[m][n][r]);
          else
            ((float*)C)[(long)row * ldc + col] = acc[m][n][r];
        }
      }
    }
}

// ---------------- RoPE cos/sin table: ctab[s*32+i] = {cos,sin}(s * theta^(-i/32)) ----------------
__global__ __launch_bounds__(256) void rope_tab_kernel(float2* __restrict__ ctab) {
  int idx = blockIdx.x * 256 + threadIdx.x;  // 65536 = 2048 s x 32 i
  int i = idx & 31, s = idx >> 5;
  float freq = exp2f(-(float)i * (13.287712379549449f / 32.0f));
  float sn, cs;
  sincosf((float)s * freq, &sn, &cs);
  ctab[idx] = make_float2(cs, sn);
}

// ------------- K repack to fragment-major + fused RoPE -------------
// Kp chunk idx = [b][kvh][t][n][half][lane], 16B each; attn reads contiguous
// (base + lane*16). Source Ks[b*2048+s][512] row-major; s = t*64+n*16+l15,
// d = half*32 + l4*8 + j.
__global__ __launch_bounds__(256) void kpack_kernel(const u16* __restrict__ Ks,
                                                    const float2* __restrict__ ctab,
                                                    u16* __restrict__ Kp) {
  int idx = blockIdx.x * 256 + threadIdx.x;  // 262144 chunks
  int lane = idx & 63, half = (idx >> 6) & 1, n = (idx >> 7) & 3;
  int t = (idx >> 9) & 31, kvh = (idx >> 14) & 7, b = idx >> 17;
  int l15 = lane & 15, l4 = lane >> 4;
  int s = t * 64 + n * 16 + l15;
  int d0 = half * 32 + l4 * 8;
  const u16* src = Ks + ((long)(b * 2048 + s)) * 512 + kvh * 64 + d0;
  uint4 v = *(const uint4*)src;
  const float2* ct = ctab + s * 32 + (d0 >> 1);
  uint32_t o[4];
#pragma unroll
  for (int jj = 0; jj < 4; ++jj) {
    uint32_t vw = ((const uint32_t*)&v)[jj];
    float2 cs = ct[jj];
    float e = bf2f((u16)vw), od = bf2f((u16)(vw >> 16));
    float re = e * cs.x - od * cs.y;
    float ro = e * cs.y + od * cs.x;
    o[jj] = (uint32_t)f2bf(re) | ((uint32_t)f2bf(ro) << 16);
  }
  *(uint4*)(Kp + (long)idx * 8) = *(uint4*)o;
}

// ------------- V repack to fragment-major -------------
// Vp chunk idx = [b][kvh][t][f][half][lane]; element (lane,j) = V^T[d][s] with
// d = f*16+l15, s = t*64 + half*32 + l4*8 + j. Source Vt[b][kvh][d][s] (s-contig).
__global__ __launch_bounds__(256) void vpack_kernel(const u16* __restrict__ Vt,
                                                    u16* __restrict__ Vp) {
  int idx = blockIdx.x * 256 + threadIdx.x;  // 262144 chunks
  int lane = idx & 63, half = (idx >> 6) & 1, f = (idx >> 7) & 3;
  int t = (idx >> 9) & 31, kvh = (idx >> 14) & 7, b = idx >> 17;
  int l15 = lane & 15, l4 = lane >> 4;
  const u16* src = Vt + ((long)((b * 8 + kvh) * 64 + f * 16 + l15)) * 2048 +
                   t * 64 + half * 32 + l4 * 8;
  *(uint4*)(Vp + (long)idx * 8) = *(const uint4*)src;
}

// ---------------- Flash attention v5 (causal, GQA 4:1, fragment-major K/V) ----------------
// Identical structure to v4 (per-lane softmax, chunk-rotated balance, 8 waves/SIMD),
// but K/V fragment loads are now contiguous 1KB per instruction (base + lane*16B)
// from packed Kp/Vp -- removes the TA gather wall (64cy -> 16cy per VMEM).
// Per-tile stride in Kp/Vp: 4 x 2 x 64 x 8 = 4096 u16.
__global__ __launch_bounds__(256, 8) void attn_kernel(const u16* __restrict__ Q,
                                                      const u16* __restrict__ Kp,
                                                      const u16* __restrict__ Vp,
                                                      const float2* __restrict__ ctab,
                                                      u16* __restrict__ O) {
  int bid = blockIdx.x;
  int p = bid & 31, h = (bid >> 5) & 31, b = bid >> 10;
  int kvh = h >> 2;
  int tid = threadIdx.x, lane = tid & 63, w = tid >> 6;
  int l15 = lane & 15, l4 = lane >> 4;
  int cc = (w + p) & 3;  // rotate chunk->wave-slot so SIMDs mix lengths
  int c = cc == 0 ? 2 * p : cc == 1 ? 2 * p + 1 : cc == 2 ? 127 - 2 * p : 126 - 2 * p;
  int qb = c * 16;
  int nt = (c >> 2) + 1;  // kv tiles of 64
  __shared__ u16 Ps[4][16][72];  // per-wave P tile [q][k], stride 72
  u16(*myPs)[72] = Ps[w];
  const u16* Qh = Q + (long)b * S_LEN * 2048 + h * 64;
  const u16* Kh = Kp + (long)(b * 8 + kvh) * 131072;  // 32t x 4n x 2half x 64lane x 8
  const u16* Vh = Vp + (long)(b * 8 + kvh) * 131072;
  u16* Oh = O + (long)b * S_LEN * 2048 + h * 64;
  // ---- load Q row (q = qb+l15) and apply RoPE in-register (scale folds 1/sqrt(64))
  int s = qb + l15;
  const u16* qp = Qh + (long)s * 2048;
  uint4 r0 = *(const uint4*)(qp + l4 * 8);       // pairs i = l4*4 + jj
  uint4 r1 = *(const uint4*)(qp + 32 + l4 * 8);  // pairs i = 16 + l4*4 + jj
  const float2* ct = ctab + (long)s * 32 + l4 * 4;
  uint32_t q0w[4], q1w[4];
#pragma unroll
  for (int jj = 0; jj < 4; ++jj) {
    float2 cs0 = ct[jj], cs1 = ct[16 + jj];
    uint32_t v0 = ((const uint32_t*)&r0)[jj], v1 = ((const uint32_t*)&r1)[jj];
    float e0 = bf2f((u16)v0), o0 = bf2f((u16)(v0 >> 16));
    float e1 = bf2f((u16)v1), o1 = bf2f((u16)(v1 >> 16));
    float a0 = (e0 * cs0.x - o0 * cs0.y) * 0.125f;
    float b0 = (e0 * cs0.y + o0 * cs0.x) * 0.125f;
    float a1 = (e1 * cs1.x - o1 * cs1.y) * 0.125f;
    float b1 = (e1 * cs1.y + o1 * cs1.x) * 0.125f;
    q0w[jj] = (uint32_t)f2bf(a0) | ((uint32_t)f2bf(b0) << 16);
    q1w[jj] = (uint32_t)f2bf(a1) | ((uint32_t)f2bf(b1) << 16);
  }
  bf16x8 qf0 = __builtin_bit_cast(bf16x8, *(uint4*)q0w);
  bf16x8 qf1 = __builtin_bit_cast(bf16x8, *(uint4*)q1w);
  float m_r = -INFINITY, l_r = 0.f;
  f32x4 oaccT[4] = {};
  int lane8 = lane * 8;
  for (int t = 0; t < nt; ++t) {
    const u16* kt = Kh + t * 4096;  // 4n x 2half x 512
    f32x4 sacc[4] = {};
#pragma unroll
    for (int n = 0; n < 4; ++n) {  // S^T[64k][16q]; contiguous 1KB frag loads
      sacc[n] = mfma16(ldfrag(kt + n * 1024 + lane8), qf0, sacc[n]);
      sacc[n] = mfma16(ldfrag(kt + n * 1024 + 512 + lane8), qf1, sacc[n]);
    }
    if (t == nt - 1) {  // causal mask: k = t*64+n*16+l4*4+r, q = qb+l15
      int kb = t * 64;
#pragma unroll
      for (int n = 0; n < 4; ++n) {
        int kc_ = kb + n * 16 + l4 * 4;
#pragma unroll
        for (int r = 0; r < 4; ++r)
          if (kc_ + r > qb + l15) sacc[n][r] = -1e30f;
      }
    }
    // per-lane max over the 16 owned k-scores (same q), then across l4 groups
    float mx = fmaxf(fmaxf(fmaxf(sacc[0][0], sacc[0][1]), fmaxf(sacc[0][2], sacc[0][3])),
                     fmaxf(fmaxf(sacc[1][0], sacc[1][1]), fmaxf(sacc[1][2], sacc[1][3])));
    mx = fmaxf(mx, fmaxf(fmaxf(fmaxf(sacc[2][0], sacc[2][1]), fmaxf(sacc[2][2], sacc[2][3])),
                         fmaxf(fmaxf(sacc[3][0], sacc[3][1]), fmaxf(sacc[3][2], sacc[3][3]))));
    mx = fmaxf(mx, __shfl_xor(mx, 16));
    mx = fmaxf(mx, __shfl_xor(mx, 32));
    float mn = fmaxf(m_r, mx);
    float fac = __expf(m_r - mn);
    m_r = mn;
    float rs = 0.f;
#pragma unroll
    for (int n = 0; n < 4; ++n) {
      float p0 = __expf(sacc[n][0] - mn);
      float p1 = __expf(sacc[n][1] - mn);
      float p2 = __expf(sacc[n][2] - mn);
      float p3 = __expf(sacc[n][3] - mn);
      rs += (p0 + p1) + (p2 + p3);
      ushort4 pk;
      pk.x = f2bf(p0); pk.y = f2bf(p1); pk.z = f2bf(p2); pk.w = f2bf(p3);
      *(ushort4*)&myPs[l15][n * 16 + l4 * 4] = pk;
    }
    rs += __shfl_xor(rs, 16);
    rs += __shfl_xor(rs, 32);
    l_r = l_r * fac + rs;
#pragma unroll
    for (int f = 0; f < 4; ++f) {  // O^T rescale: per-lane fac (q = l15)
      oaccT[f][0] *= fac; oaccT[f][1] *= fac;
      oaccT[f][2] *= fac; oaccT[f][3] *= fac;
    }
    bf16x8 pa0 = ldfrag(&myPs[l15][l4 * 8]);
    bf16x8 pa1 = ldfrag(&myPs[l15][32 + l4 * 8]);
    const u16* vt = Vh + t * 4096;  // 4f x 2half x 512
#pragma unroll
    for (int f = 0; f < 4; ++f) {  // O^T[64d][16q] += V^T * P^T; contiguous frags
      oaccT[f] = mfma16(ldfrag(vt + f * 1024 + lane8), pa0, oaccT[f]);
      oaccT[f] = mfma16(ldfrag(vt + f * 1024 + 512 + lane8), pa1, oaccT[f]);
    }
  }
  float linv = 1.f / l_r;  // per-lane (q = l15)
#pragma unroll
  for (int f = 0; f < 4; ++f) {
    ushort4 pk;
    pk.x = f2bf(oaccT[f][0] * linv); pk.y = f2bf(oaccT[f][1] * linv);
    pk.z = f2bf(oaccT[f][2] * linv); pk.w = f2bf(oaccT[f][3] * linv);
    *(ushort4*)&Oh[(long)(qb + l15) * 2048 + f * 16 + l4 * 4] = pk;  // 8B store
  }
}

// ---------------- launch ----------------
extern "C" void kernel_launch(void* const* d_in, const int* in_sizes, int n_in,
                              void* d_out, int out_size, void* d_ws, size_t ws_size,
                              hipStream_t stream) {
  const float* x = (const float*)d_in[0];
  const float* Wq = (const float*)d_in[1];
  const float* Wk = (const float*)d_in[2];
  const float* Wv = (const float*)d_in[3];
  const float* Wo = (const float*)d_in[4];
  float* out = (float*)d_out;
  char* ws = (char*)d_ws;
  // workspace layout (bytes)
  u16* xb = (u16*)(ws + 0);          // 4096x2048 bf16   (16 MiB)
  u16* WqT = (u16*)(ws + 16777216);  // 2048x2048        (8 MiB) [dead after gemmQ]
  u16* WkT = (u16*)(ws + 25165824);  // 512x2048         (2 MiB)
  u16* WvT = (u16*)(ws + 27262976);  // 512x2048         (2 MiB)
  u16* WoT = (u16*)(ws + 29360128);  // 2048x2048        (8 MiB)
  u16* Qs = (u16*)(ws + 37748736);   // 4096x2048        (16 MiB)
  u16* Ks = (u16*)(ws + 54525952);   // 4096x512         (4 MiB)
  u16* Vt = (u16*)(ws + 58720256);   // [2][8][64][2048] (4 MiB) transposed V
  u16* Os = (u16*)(ws + 62914560);   // 4096x2048        (16 MiB) [ends 79691776]
  u16* Kp = (u16*)(ws + 16777216);   // packed K (4 MiB) -- aliases WqT after gemmQ
  u16* Vp = (u16*)(ws + 20971520);   // packed V (4 MiB) -- aliases WqT tail
  float2* ctab = (float2*)(ws + 79691776);  // 2048x32 cos/sin (512 KiB), AFTER Os

  cvt_kernel<<<8192, 256, 0, stream>>>(x, xb, 2097152);
  cvtT_kernel<<<dim3(64, 64), 256, 0, stream>>>(Wq, WqT, 2048, 2048);
  cvtT_kernel<<<dim3(16, 64), 256, 0, stream>>>(Wk, WkT, 2048, 512);
  cvtT_kernel<<<dim3(16, 64), 256, 0, stream>>>(Wv, WvT, 2048, 512);
  cvtT_kernel<<<dim3(64, 64), 256, 0, stream>>>(Wo, WoT, 2048, 2048);
  rope_tab_kernel<<<256, 256, 0, stream>>>(ctab);
  gemm_bt<1><<<dim3(32, 16), 256, 0, stream>>>(xb, WqT, Qs, 2048, 2048);
  gemm_bt<1><<<dim3(32, 4), 256, 0, stream>>>(xb, WkT, Ks, 2048, 512);
  gemm_bt<2><<<dim3(32, 4), 256, 0, stream>>>(xb, WvT, Vt, 2048, 512);
  kpack_kernel<<<1024, 256, 0, stream>>>(Ks, ctab, Kp);  // fuses RoPE-K
  vpack_kernel<<<1024, 256, 0, stream>>>(Vt, Vp);
  attn_kernel<<<2048, 256, 0, stream>>>(Qs, Kp, Vp, ctab, Os);
  gemm_bt<0><<<dim3(32, 16), 256, 0, stream>>>(Os, WoT, out, 2048, 2048);
}

// Round 9
// 369.340 us; speedup vs baseline: 1.7953x; 1.2237x over previous
//
#include <hip/hip_runtime.h>
#include <cstdint>

typedef unsigned short u16;
typedef __attribute__((ext_vector_type(8))) __bf16 bf16x8;
typedef __attribute__((ext_vector_type(4))) float f32x4;

#define S_LEN 2048

__device__ __forceinline__ u16 f2bf(float f) {
  uint32_t u = __builtin_bit_cast(uint32_t, f);
  u += 0x7fffu + ((u >> 16) & 1u);
  return (u16)(u >> 16);
}
__device__ __forceinline__ float bf2f(u16 h) {
  return __builtin_bit_cast(float, (uint32_t)h << 16);
}
__device__ __forceinline__ bf16x8 ldfrag(const u16* p) {
  return __builtin_bit_cast(bf16x8, *(const uint4*)p);
}
__device__ __forceinline__ f32x4 mfma16(bf16x8 a, bf16x8 b, f32x4 c) {
  return __builtin_amdgcn_mfma_f32_16x16x32_bf16(a, b, c, 0, 0, 0);
}
// async 16B global -> LDS (dest = wave-uniform base + lane*16)
__device__ __forceinline__ void glds16(const u16* g, u16* l) {
  __builtin_amdgcn_global_load_lds((const __attribute__((address_space(1))) void*)g,
                                   (__attribute__((address_space(3))) void*)l, 16, 0, 0);
}

// ---------------- fp32 -> bf16 convert (vectorized) ----------------
__global__ __launch_bounds__(256) void cvt_kernel(const float* __restrict__ in,
                                                  u16* __restrict__ out, int n4) {
  int i = blockIdx.x * 256 + threadIdx.x;
  if (i >= n4) return;
  float4 v = ((const float4*)in)[i];
  ushort4 o;
  o.x = f2bf(v.x); o.y = f2bf(v.y); o.z = f2bf(v.z); o.w = f2bf(v.w);
  ((ushort4*)out)[i] = o;
}

// ------------- fp32 W[K][N] -> bf16 Wt[N][K] (transpose-convert) -------------
__global__ __launch_bounds__(256) void cvtT_kernel(const float* __restrict__ W,
                                                   u16* __restrict__ Wt, int K, int N) {
  __shared__ float t[32][33];
  int tx = threadIdx.x & 31, ty = threadIdx.x >> 5;  // ty 0..7
  int n0 = blockIdx.x * 32, k0 = blockIdx.y * 32;
#pragma unroll
  for (int j = 0; j < 4; ++j)
    t[ty + 8 * j][tx] = W[(long)(k0 + ty + 8 * j) * N + n0 + tx];
  __syncthreads();
#pragma unroll
  for (int j = 0; j < 4; ++j)
    Wt[(long)(n0 + ty + 8 * j) * K + k0 + tx] = f2bf(t[tx][ty + 8 * j]);
}

// ------------- GEMM: C = A[M][K](bf16) * Bt[N][K]^T(bf16) -------------
// 128x128 tile, 4 waves (2x2), BK=32. 3-buffer LDS, depth-2 async pipeline:
// per K-step {stage(t+2) -> compute buf(t%3) -> vmcnt(4) -> s_barrier}.
// MODE: 0 = fp32 out row-major; 3 = fused QKV epilogue (Q rows / K rows / Vt^T
// by block-uniform column region).
template <int MODE>
__global__ __launch_bounds__(256) void gemm_bt(const u16* __restrict__ A,
                                               const u16* __restrict__ Bt,
                                               void* __restrict__ C, int K, int ldc,
                                               u16* __restrict__ Kc_out,
                                               u16* __restrict__ Vt_out) {
  __shared__ __align__(16) u16 As[3][4096];
  __shared__ __align__(16) u16 Bs[3][4096];
  int tid = threadIdx.x;
  int lane = tid & 63, w = tid >> 6;
  int wr = (w >> 1) * 64, wc = (w & 1) * 64;
  int l15 = lane & 15, l4 = lane >> 4;
  int rowbase = blockIdx.x * 128, colbase = blockIdx.y * 128;
  f32x4 acc[4][4] = {};
  int r0 = tid >> 2, kc0 = (tid & 3) * 8;
  const u16* Ap0 = A + (long)(rowbase + r0) * K + kc0;
  const u16* Ap1 = A + (long)(rowbase + 64 + r0) * K + kc0;
  const u16* Bp0 = Bt + (long)(colbase + r0) * K + kc0;
  const u16* Bp1 = Bt + (long)(colbase + 64 + r0) * K + kc0;
  int wb = w * 512;  // wave-uniform LDS base (64 lanes x 16B = 1KB per wave)
  auto stage = [&](int t, int buf) {
    int ko = t * 32;
    glds16(Ap0 + ko, &As[buf][wb]);
    glds16(Ap1 + ko, &As[buf][2048 + wb]);
    glds16(Bp0 + ko, &Bs[buf][wb]);
    glds16(Bp1 + ko, &Bs[buf][2048 + wb]);
  };
  int nk = K >> 5;  // 64
  stage(0, 0);
  stage(1, 1);
  asm volatile("s_waitcnt vmcnt(4)" ::: "memory");
  __builtin_amdgcn_s_barrier();
  int cur = 0, nxt2 = 2;
  for (int t = 0; t < nk; ++t) {
    if (t + 2 < nk) stage(t + 2, nxt2);
    bf16x8 af[4], bv[4];
#pragma unroll
    for (int m = 0; m < 4; ++m) af[m] = ldfrag(&As[cur][(wr + m * 16 + l15) * 32 + l4 * 8]);
#pragma unroll
    for (int n = 0; n < 4; ++n) bv[n] = ldfrag(&Bs[cur][(wc + n * 16 + l15) * 32 + l4 * 8]);
#pragma unroll
    for (int m = 0; m < 4; ++m)
#pragma unroll
      for (int n = 0; n < 4; ++n) acc[m][n] = mfma16(af[m], bv[n], acc[m][n]);
    if (t + 1 < nk) {
      if (t + 2 < nk)
        asm volatile("s_waitcnt vmcnt(4)" ::: "memory");
      else
        asm volatile("s_waitcnt vmcnt(0)" ::: "memory");
      __builtin_amdgcn_s_barrier();
    }
    cur = cur == 2 ? 0 : cur + 1;
    nxt2 = nxt2 == 2 ? 0 : nxt2 + 1;
  }
  if (MODE == 0) {
#pragma unroll
    for (int m = 0; m < 4; ++m)
#pragma unroll
      for (int n = 0; n < 4; ++n)
#pragma unroll
        for (int r = 0; r < 4; ++r) {
          int row = rowbase + wr + m * 16 + l4 * 4 + r;
          int col = colbase + wc + n * 16 + l15;
          ((float*)C)[(long)row * ldc + col] = acc[m][n][r];
        }
  } else {  // MODE 3: fused QKV epilogue, block-uniform region select
    if (colbase < 2048) {  // Q rows (bf16, ld 2048)
#pragma unroll
      for (int m = 0; m < 4; ++m)
#pragma unroll
        for (int n = 0; n < 4; ++n)
#pragma unroll
          for (int r = 0; r < 4; ++r) {
            int row = rowbase + wr + m * 16 + l4 * 4 + r;
            int col = colbase + wc + n * 16 + l15;
            ((u16*)C)[(long)row * 2048 + col] = f2bf(acc[m][n][r]);
          }
    } else if (colbase < 2560) {  // K rows (bf16, ld 512)
#pragma unroll
      for (int m = 0; m < 4; ++m)
#pragma unroll
        for (int n = 0; n < 4; ++n)
#pragma unroll
          for (int r = 0; r < 4; ++r) {
            int row = rowbase + wr + m * 16 + l4 * 4 + r;
            int col = colbase + wc + n * 16 + l15 - 2048;
            Kc_out[(long)row * 512 + col] = f2bf(acc[m][n][r]);
          }
    } else {  // V -> Vt[b][kvh][d][s] transposed, 8B stores
#pragma unroll
      for (int m = 0; m < 4; ++m)
#pragma unroll
        for (int n = 0; n < 4; ++n) {
          int row = rowbase + wr + m * 16 + l4 * 4;  // = b*2048 + s, s%4==0
          int col = colbase + wc + n * 16 + l15 - 2560;  // = kvh*64 + d
          int b_ = row >> 11, s_ = row & 2047;
          int kvh_ = col >> 6, d_ = col & 63;
          ushort4 pk;
          pk.x = f2bf(acc[m][n][0]); pk.y = f2bf(acc[m][n][1]);
          pk.z = f2bf(acc[m][n][2]); pk.w = f2bf(acc[m][n][3]);
          *(ushort4*)&Vt_out[((long)((b_ * 8 + kvh_) * 64 + d_)) * 2048 + s_] = pk;
        }
    }
  }
}

// ---------------- RoPE cos/sin table: ctab[s*32+i] = {cos,sin}(s * theta^(-i/32)) ----------------
__global__ __launch_bounds__(256) void rope_tab_kernel(float2* __restrict__ ctab) {
  int idx = blockIdx.x * 256 + threadIdx.x;  // 65536 = 2048 s x 32 i
  int i = idx & 31, s = idx >> 5;
  float freq = exp2f(-(float)i * (13.287712379549449f / 32.0f));
  float sn, cs;
  sincosf((float)s * freq, &sn, &cs);
  ctab[idx] = make_float2(cs, sn);
}

// ------------- K repack to fragment-major + fused RoPE -------------
__global__ __launch_bounds__(256) void kpack_kernel(const u16* __restrict__ Ks,
                                                    const float2* __restrict__ ctab,
                                                    u16* __restrict__ Kp) {
  int idx = blockIdx.x * 256 + threadIdx.x;  // 262144 chunks
  int lane = idx & 63, half = (idx >> 6) & 1, n = (idx >> 7) & 3;
  int t = (idx >> 9) & 31, kvh = (idx >> 14) & 7, b = idx >> 17;
  int l15 = lane & 15, l4 = lane >> 4;
  int s = t * 64 + n * 16 + l15;
  int d0 = half * 32 + l4 * 8;
  const u16* src = Ks + ((long)(b * 2048 + s)) * 512 + kvh * 64 + d0;
  uint4 v = *(const uint4*)src;
  const float2* ct = ctab + s * 32 + (d0 >> 1);
  uint32_t o[4];
#pragma unroll
  for (int jj = 0; jj < 4; ++jj) {
    uint32_t vw = ((const uint32_t*)&v)[jj];
    float2 cs = ct[jj];
    float e = bf2f((u16)vw), od = bf2f((u16)(vw >> 16));
    float re = e * cs.x - od * cs.y;
    float ro = e * cs.y + od * cs.x;
    o[jj] = (uint32_t)f2bf(re) | ((uint32_t)f2bf(ro) << 16);
  }
  *(uint4*)(Kp + (long)idx * 8) = *(uint4*)o;
}

// ------------- V repack to fragment-major -------------
__global__ __launch_bounds__(256) void vpack_kernel(const u16* __restrict__ Vt,
                                                    u16* __restrict__ Vp) {
  int idx = blockIdx.x * 256 + threadIdx.x;  // 262144 chunks
  int lane = idx & 63, half = (idx >> 6) & 1, f = (idx >> 7) & 3;
  int t = (idx >> 9) & 31, kvh = (idx >> 14) & 7, b = idx >> 17;
  int l15 = lane & 15, l4 = lane >> 4;
  const u16* src = Vt + ((long)((b * 8 + kvh) * 64 + f * 16 + l15)) * 2048 +
                   t * 64 + half * 32 + l4 * 8;
  *(uint4*)(Vp + (long)idx * 8) = *(const uint4*)src;
}

// ---------------- Flash attention v5 (causal, GQA 4:1, fragment-major K/V) ----------------
__global__ __launch_bounds__(256, 8) void attn_kernel(const u16* __restrict__ Q,
                                                      const u16* __restrict__ Kp,
                                                      const u16* __restrict__ Vp,
                                                      const float2* __restrict__ ctab,
                                                      u16* __restrict__ O) {
  int bid = blockIdx.x;
  int p = bid & 31, h = (bid >> 5) & 31, b = bid >> 10;
  int kvh = h >> 2;
  int tid = threadIdx.x, lane = tid & 63, w = tid >> 6;
  int l15 = lane & 15, l4 = lane >> 4;
  int cc = (w + p) & 3;  // rotate chunk->wave-slot so SIMDs mix lengths
  int c = cc == 0 ? 2 * p : cc == 1 ? 2 * p + 1 : cc == 2 ? 127 - 2 * p : 126 - 2 * p;
  int qb = c * 16;
  int nt = (c >> 2) + 1;  // kv tiles of 64
  __shared__ u16 Ps[4][16][72];  // per-wave P tile [q][k], stride 72
  u16(*myPs)[72] = Ps[w];
  const u16* Qh = Q + (long)b * S_LEN * 2048 + h * 64;
  const u16* Kh = Kp + (long)(b * 8 + kvh) * 131072;  // 32t x 4n x 2half x 64lane x 8
  const u16* Vh = Vp + (long)(b * 8 + kvh) * 131072;
  u16* Oh = O + (long)b * S_LEN * 2048 + h * 64;
  // ---- load Q row (q = qb+l15) and apply RoPE in-register (scale folds 1/sqrt(64))
  int s = qb + l15;
  const u16* qp = Qh + (long)s * 2048;
  uint4 r0 = *(const uint4*)(qp + l4 * 8);       // pairs i = l4*4 + jj
  uint4 r1 = *(const uint4*)(qp + 32 + l4 * 8);  // pairs i = 16 + l4*4 + jj
  const float2* ct = ctab + (long)s * 32 + l4 * 4;
  uint32_t q0w[4], q1w[4];
#pragma unroll
  for (int jj = 0; jj < 4; ++jj) {
    float2 cs0 = ct[jj], cs1 = ct[16 + jj];
    uint32_t v0 = ((const uint32_t*)&r0)[jj], v1 = ((const uint32_t*)&r1)[jj];
    float e0 = bf2f((u16)v0), o0 = bf2f((u16)(v0 >> 16));
    float e1 = bf2f((u16)v1), o1 = bf2f((u16)(v1 >> 16));
    float a0 = (e0 * cs0.x - o0 * cs0.y) * 0.125f;
    float b0 = (e0 * cs0.y + o0 * cs0.x) * 0.125f;
    float a1 = (e1 * cs1.x - o1 * cs1.y) * 0.125f;
    float b1 = (e1 * cs1.y + o1 * cs1.x) * 0.125f;
    q0w[jj] = (uint32_t)f2bf(a0) | ((uint32_t)f2bf(b0) << 16);
    q1w[jj] = (uint32_t)f2bf(a1) | ((uint32_t)f2bf(b1) << 16);
  }
  bf16x8 qf0 = __builtin_bit_cast(bf16x8, *(uint4*)q0w);
  bf16x8 qf1 = __builtin_bit_cast(bf16x8, *(uint4*)q1w);
  float m_r = -INFINITY, l_r = 0.f;
  f32x4 oaccT[4] = {};
  int lane8 = lane * 8;
  for (int t = 0; t < nt; ++t) {
    const u16* kt = Kh + t * 4096;  // 4n x 2half x 512
    f32x4 sacc[4] = {};
#pragma unroll
    for (int n = 0; n < 4; ++n) {  // S^T[64k][16q]; contiguous 1KB frag loads
      sacc[n] = mfma16(ldfrag(kt + n * 1024 + lane8), qf0, sacc[n]);
      sacc[n] = mfma16(ldfrag(kt + n * 1024 + 512 + lane8), qf1, sacc[n]);
    }
    if (t == nt - 1) {  // causal mask: k = t*64+n*16+l4*4+r, q = qb+l15
      int kb = t * 64;
#pragma unroll
      for (int n = 0; n < 4; ++n) {
        int kc_ = kb + n * 16 + l4 * 4;
#pragma unroll
        for (int r = 0; r < 4; ++r)
          if (kc_ + r > qb + l15) sacc[n][r] = -1e30f;
      }
    }
    float mx = fmaxf(fmaxf(fmaxf(sacc[0][0], sacc[0][1]), fmaxf(sacc[0][2], sacc[0][3])),
                     fmaxf(fmaxf(sacc[1][0], sacc[1][1]), fmaxf(sacc[1][2], sacc[1][3])));
    mx = fmaxf(mx, fmaxf(fmaxf(fmaxf(sacc[2][0], sacc[2][1]), fmaxf(sacc[2][2], sacc[2][3])),
                         fmaxf(fmaxf(sacc[3][0], sacc[3][1]), fmaxf(sacc[3][2], sacc[3][3]))));
    mx = fmaxf(mx, __shfl_xor(mx, 16));
    mx = fmaxf(mx, __shfl_xor(mx, 32));
    float mn = fmaxf(m_r, mx);
    float fac = __expf(m_r - mn);
    m_r = mn;
    float rs = 0.f;
#pragma unroll
    for (int n = 0; n < 4; ++n) {
      float p0 = __expf(sacc[n][0] - mn);
      float p1 = __expf(sacc[n][1] - mn);
      float p2 = __expf(sacc[n][2] - mn);
      float p3 = __expf(sacc[n][3] - mn);
      rs += (p0 + p1) + (p2 + p3);
      ushort4 pk;
      pk.x = f2bf(p0); pk.y = f2bf(p1); pk.z = f2bf(p2); pk.w = f2bf(p3);
      *(ushort4*)&myPs[l15][n * 16 + l4 * 4] = pk;
    }
    rs += __shfl_xor(rs, 16);
    rs += __shfl_xor(rs, 32);
    l_r = l_r * fac + rs;
#pragma unroll
    for (int f = 0; f < 4; ++f) {  // O^T rescale: per-lane fac (q = l15)
      oaccT[f][0] *= fac; oaccT[f][1] *= fac;
      oaccT[f][2] *= fac; oaccT[f][3] *= fac;
    }
    bf16x8 pa0 = ldfrag(&myPs[l15][l4 * 8]);
    bf16x8 pa1 = ldfrag(&myPs[l15][32 + l4 * 8]);
    const u16* vt = Vh + t * 4096;  // 4f x 2half x 512
#pragma unroll
    for (int f = 0; f < 4; ++f) {  // O^T[64d][16q] += V^T * P^T; contiguous frags
      oaccT[f] = mfma16(ldfrag(vt + f * 1024 + lane8), pa0, oaccT[f]);
      oaccT[f] = mfma16(ldfrag(vt + f * 1024 + 512 + lane8), pa1, oaccT[f]);
    }
  }
  float linv = 1.f / l_r;  // per-lane (q = l15)
#pragma unroll
  for (int f = 0; f < 4; ++f) {
    ushort4 pk;
    pk.x = f2bf(oaccT[f][0] * linv); pk.y = f2bf(oaccT[f][1] * linv);
    pk.z = f2bf(oaccT[f][2] * linv); pk.w = f2bf(oaccT[f][3] * linv);
    *(ushort4*)&Oh[(long)(qb + l15) * 2048 + f * 16 + l4 * 4] = pk;  // 8B store
  }
}

// ---------------- launch ----------------
extern "C" void kernel_launch(void* const* d_in, const int* in_sizes, int n_in,
                              void* d_out, int out_size, void* d_ws, size_t ws_size,
                              hipStream_t stream) {
  const float* x = (const float*)d_in[0];
  const float* Wq = (const float*)d_in[1];
  const float* Wk = (const float*)d_in[2];
  const float* Wv = (const float*)d_in[3];
  const float* Wo = (const float*)d_in[4];
  float* out = (float*)d_out;
  char* ws = (char*)d_ws;
  // workspace layout (bytes)
  u16* xb = (u16*)(ws + 0);             // 4096x2048 bf16 (16 MiB) [dead after gemmQKV]
  u16* WqkvT = (u16*)(ws + 16777216);   // 3072x2048      (12 MiB) rows: Q|K|V
  u16* WoT = (u16*)(ws + 29360128);     // 2048x2048      (8 MiB)
  u16* Qs = (u16*)(ws + 37748736);      // 4096x2048      (16 MiB)
  u16* Ks = (u16*)(ws + 54525952);      // 4096x512       (4 MiB)
  u16* Vt = (u16*)(ws + 58720256);      // [2][8][64][2048] (4 MiB)
  u16* Os = (u16*)(ws + 62914560);      // 4096x2048      (16 MiB) [ends 79691776]
  u16* Kp = (u16*)(ws + 0);             // packed K (4 MiB) -- aliases dead xb
  u16* Vp = (u16*)(ws + 4194304);       // packed V (4 MiB) -- aliases dead xb
  float2* ctab = (float2*)(ws + 79691776);  // 2048x32 cos/sin (512 KiB)

  cvt_kernel<<<8192, 256, 0, stream>>>(x, xb, 2097152);
  cvtT_kernel<<<dim3(64, 64), 256, 0, stream>>>(Wq, WqkvT, 2048, 2048);
  cvtT_kernel<<<dim3(16, 64), 256, 0, stream>>>(Wk, WqkvT + 4194304, 2048, 512);
  cvtT_kernel<<<dim3(16, 64), 256, 0, stream>>>(Wv, WqkvT + 5242880, 2048, 512);
  cvtT_kernel<<<dim3(64, 64), 256, 0, stream>>>(Wo, WoT, 2048, 2048);
  rope_tab_kernel<<<256, 256, 0, stream>>>(ctab);
  gemm_bt<3><<<dim3(32, 24), 256, 0, stream>>>(xb, WqkvT, Qs, 2048, 2048, Ks, Vt);
  kpack_kernel<<<1024, 256, 0, stream>>>(Ks, ctab, Kp);  // fuses RoPE-K
  vpack_kernel<<<1024, 256, 0, stream>>>(Vt, Vp);
  attn_kernel<<<2048, 256, 0, stream>>>(Qs, Kp, Vp, ctab, Os);
  gemm_bt<0><<<dim3(32, 16), 256, 0, stream>>>(Os, WoT, out, 2048, 2048, nullptr, nullptr);
}